// Round 5
// baseline (180.696 us; speedup 1.0000x reference)
//
#include <hip/hip_runtime.h>

// (B,N,F,K) = (4096, 2048, 64, 64)
#define NB 4096
#define NN 2048
#define NF 64
#define NK 64

#define RPB   16              // rows per block
#define TPB   1024            // 16 waves
#define NWAVE 16
#define CPW   (NN / NWAVE)    // 128 contraction cols per wave
#define KS    (CPW / 32)      // 4 MFMA K-steps per wave
#define GRID  (NB / RPB)      // 256 blocks = 1 per CU

typedef short bf16x8 __attribute__((ext_vector_type(8)));  // 8 bf16 (4 VGPRs)
typedef float f32x4  __attribute__((ext_vector_type(4)));

// ws byte offsets (256B aligned)
#define OFF_VGTH 0                          // ushort [64][2048] hi
#define OFF_VGTL (OFF_VGTH + NK * NN * 2)   // ushort [64][2048] lo
#define OFF_VN   (OFF_VGTL + NK * NN * 2)   // float  [2048]
#define OFF_LINT (OFF_VN + NN * 4)          // float  [4096]
#define OFF_BP   (OFF_LINT + NB * 4)        // double [256]
#define OFF_CNT  (OFF_BP + GRID * 8)        // unsigned [1]

__device__ inline unsigned short bf16_rtn(float f) {
    unsigned u = __float_as_uint(f);
    return (unsigned short)((u + 0x7fffu + ((u >> 16) & 1u)) >> 16);
}

// ---------- k_prep: gather V rows, bf16 hi/lo split, store transposed [k][i]; zero counter ----------
__global__ __launch_bounds__(256) void k_prep(const float* __restrict__ vec,
                                              const int* __restrict__ f2f,
                                              unsigned short* __restrict__ VgTh,
                                              unsigned short* __restrict__ VgTl,
                                              float* __restrict__ vnorm,
                                              unsigned* __restrict__ cnt) {
    __shared__ unsigned short tH[64][72];
    __shared__ unsigned short tL[64][72];
    const int t  = threadIdx.x;
    const int i0 = blockIdx.x * 64;
    if (blockIdx.x == 0 && t == 0) *cnt = 0u;   // re-arm last-block counter every launch
    // phase 1: thread t loads 16 floats of feature il = t>>2
    {
        const int il = t >> 2;
        const int sg = (t & 3) * 16;
        const int i  = i0 + il;
        const int f  = f2f[i];
        const float* p = vec + (size_t)i * (NF * NK) + (size_t)f * NK + sg;
        float nsum = 0.f;
        #pragma unroll
        for (int j4 = 0; j4 < 4; ++j4) {
            float4 v = *reinterpret_cast<const float4*>(p + j4 * 4);
            float vv[4] = {v.x, v.y, v.z, v.w};
            #pragma unroll
            for (int e = 0; e < 4; ++e) {
                float x = vv[e];
                nsum = fmaf(x, x, nsum);
                unsigned xb = __float_as_uint(x);
                float hf = __uint_as_float(xb & 0xffff0000u);
                int k = sg + j4 * 4 + e;
                tH[il][k] = (unsigned short)(xb >> 16);
                tL[il][k] = bf16_rtn(x - hf);
            }
        }
        nsum += __shfl_xor(nsum, 1, 64);
        nsum += __shfl_xor(nsum, 2, 64);
        if ((t & 3) == 0) vnorm[i] = nsum;   // vnorm from EXACT fp32 values
    }
    __syncthreads();
    // phase 2: thread t writes k-row t>>2, i-segment (t&3)*16
    {
        const int k  = t >> 2;
        const int is = (t & 3) * 16;
        unsigned short hb[16], lb[16];
        #pragma unroll
        for (int j = 0; j < 16; ++j) { hb[j] = tH[is + j][k]; lb[j] = tL[is + j][k]; }
        unsigned short* ph = VgTh + (size_t)k * NN + i0 + is;
        unsigned short* pl = VgTl + (size_t)k * NN + i0 + is;
        *reinterpret_cast<uint4*>(ph)     = *reinterpret_cast<uint4*>(hb);
        *reinterpret_cast<uint4*>(ph + 8) = *reinterpret_cast<uint4*>(hb + 8);
        *reinterpret_cast<uint4*>(pl)     = *reinterpret_cast<uint4*>(lb);
        *reinterpret_cast<uint4*>(pl + 8) = *reinterpret_cast<uint4*>(lb + 8);
    }
}

// ---------- k_main: fused MFMA GEMM + row reduce + last-block finalize ----------
// block = 16 rows x full 2048 contraction; wave w owns cols [128w,128w+128).
__global__ __launch_bounds__(TPB) void k_main(const float* __restrict__ X,
                                              const float* __restrict__ Wg,
                                              const unsigned short* __restrict__ VgTh,
                                              const unsigned short* __restrict__ VgTl,
                                              const float* __restrict__ vn,
                                              const float* __restrict__ bptr,
                                              float* __restrict__ lint,
                                              double* __restrict__ bpart,
                                              unsigned* __restrict__ cnt,
                                              float* __restrict__ out) {
    __shared__ float Tl[NWAVE * 1088];   // [w][row(stride 68)][lat] : 69.6 KB, all <=2-way
    __shared__ float linW[NWAVE * 17];
    __shared__ float ddW[NWAVE * 17];
    __shared__ float rowRes[RPB];
    __shared__ float interS;
    __shared__ int   lastS;

    const int t    = threadIdx.x;
    const int w    = t >> 6;          // wave 0..15 = contraction slice
    const int lane = t & 63;
    const int m    = lane & 15;
    const int quad = lane >> 4;
    const int r0   = blockIdx.x * RPB;
    const int row  = r0 + m;
    const int cw   = w * CPW;

    const float* xp = X  + (size_t)row * NN + cw + quad * 8;
    const float* wp = Wg + cw + quad * 8;
    const float* np = vn + cw + quad * 8;
    const unsigned short* bhp = VgTh + (size_t)m * NN + cw + quad * 8;
    const unsigned short* blp = VgTl + (size_t)m * NN + cw + quad * 8;

    f32x4 acc[4];
    #pragma unroll
    for (int nt = 0; nt < 4; ++nt)
        #pragma unroll
        for (int e = 0; e < 4; ++e) acc[nt][e] = 0.f;
    float lin = 0.f, dd = 0.f;

    #pragma unroll
    for (int s = 0; s < KS; ++s) {
        float4 xa = *reinterpret_cast<const float4*>(xp + s * 32);
        float4 xb = *reinterpret_cast<const float4*>(xp + s * 32 + 4);
        float4 wa = *reinterpret_cast<const float4*>(wp + s * 32);
        float4 wb = *reinterpret_cast<const float4*>(wp + s * 32 + 4);
        float4 na = *reinterpret_cast<const float4*>(np + s * 32);
        float4 nb = *reinterpret_cast<const float4*>(np + s * 32 + 4);

        float xs8[8] = {xa.x, xa.y, xa.z, xa.w, xb.x, xb.y, xb.z, xb.w};
        float ws8[8] = {wa.x, wa.y, wa.z, wa.w, wb.x, wb.y, wb.z, wb.w};
        float ns8[8] = {na.x, na.y, na.z, na.w, nb.x, nb.y, nb.z, nb.w};

        #pragma unroll
        for (int j = 0; j < 8; ++j) {
            lin = fmaf(xs8[j], ws8[j], lin);
            dd  = fmaf(xs8[j] * xs8[j], ns8[j], dd);
        }

        bf16x8 ah, al;
        #pragma unroll
        for (int j = 0; j < 8; ++j) {
            unsigned ub = __float_as_uint(xs8[j]);
            ah[j] = (short)(ub >> 16);
            float hf = __uint_as_float(ub & 0xffff0000u);
            al[j] = (short)bf16_rtn(xs8[j] - hf);
        }

        #pragma unroll
        for (int nt = 0; nt < 4; ++nt) {
            bf16x8 bh = *reinterpret_cast<const bf16x8*>(bhp + (size_t)nt * 16 * NN + s * 32);
            bf16x8 bl = *reinterpret_cast<const bf16x8*>(blp + (size_t)nt * 16 * NN + s * 32);
            acc[nt] = __builtin_amdgcn_mfma_f32_16x16x32_bf16(ah, bh, acc[nt], 0, 0, 0);
            acc[nt] = __builtin_amdgcn_mfma_f32_16x16x32_bf16(al, bh, acc[nt], 0, 0, 0);
            acc[nt] = __builtin_amdgcn_mfma_f32_16x16x32_bf16(ah, bl, acc[nt], 0, 0, 0);
        }
    }

    // ---- stash wave-partial T tile: C-layout row=quad*4+r, col=nt*16+m ----
    #pragma unroll
    for (int nt = 0; nt < 4; ++nt)
        #pragma unroll
        for (int r = 0; r < 4; ++r)
            Tl[w * 1088 + (quad * 4 + r) * 68 + nt * 16 + m] = acc[nt][r];

    lin += __shfl_xor(lin, 16, 64); lin += __shfl_xor(lin, 32, 64);
    dd  += __shfl_xor(dd, 16, 64);  dd  += __shfl_xor(dd, 32, 64);
    if (quad == 0) { linW[w * 17 + m] = lin; ddW[w * 17 + m] = dd; }
    __syncthreads();

    // ---- per-row phase: wave w owns row w; lane = latent k ----
    {
        float ts = 0.f;
        #pragma unroll
        for (int ww = 0; ww < NWAVE; ++ww)
            ts += Tl[ww * 1088 + w * 68 + lane];
        float s2 = ts * ts;
        #pragma unroll
        for (int d = 1; d < 64; d <<= 1) s2 += __shfl_xor(s2, d, 64);
        float lw = (lane < 16) ? linW[lane * 17 + w] : 0.f;
        float dw = (lane < 16) ? ddW [lane * 17 + w] : 0.f;
        #pragma unroll
        for (int d = 1; d < 16; d <<= 1) {
            lw += __shfl_xor(lw, d, 64);
            dw += __shfl_xor(dw, d, 64);
        }
        if (lane == 0) {
            lint[r0 + w] = lw;          // per-row linear part
            rowRes[w]    = s2 - dw;     // per-row interaction partial
        }
    }
    __syncthreads();

    if (t == 0) {
        double p = 0.0;
        #pragma unroll
        for (int r = 0; r < RPB; ++r) p += (double)rowRes[r];
        bpart[blockIdx.x] = p;
    }
    __threadfence();          // release: lint + bpart globally visible
    __syncthreads();
    if (t == 0) {
        unsigned old = atomicAdd(cnt, 1u);   // device-scope
        lastS = (old == GRID - 1) ? 1 : 0;
    }
    __syncthreads();

    if (lastS) {
        __threadfence();      // acquire
        if (w == 0) {
            double p = 0.0;
            #pragma unroll
            for (int j = 0; j < 4; ++j) p += bpart[lane * 4 + j];
            #pragma unroll
            for (int d = 1; d < 64; d <<= 1) p += __shfl_xor(p, d, 64);
            if (lane == 0) interS = (float)(0.5 * p);
        }
        __syncthreads();
        float inter = interS;
        float bias  = bptr[0];
        #pragma unroll
        for (int j = 0; j < NB / TPB; ++j)
            out[t + j * TPB] = lint[t + j * TPB] + bias + inter;
    }
}

extern "C" void kernel_launch(void* const* d_in, const int* in_sizes, int n_in,
                              void* d_out, int out_size, void* d_ws, size_t ws_size,
                              hipStream_t stream) {
    const float* X    = (const float*)d_in[0];
    const float* W    = (const float*)d_in[1];
    const float* bias = (const float*)d_in[2];
    const float* vec  = (const float*)d_in[3];
    const int*   f2f  = (const int*)d_in[4];
    float* out = (float*)d_out;

    char* base = (char*)d_ws;
    unsigned short* VgTh = (unsigned short*)(base + OFF_VGTH);
    unsigned short* VgTl = (unsigned short*)(base + OFF_VGTL);
    float*    vnorm = (float*)   (base + OFF_VN);
    float*    lint  = (float*)   (base + OFF_LINT);
    double*   bpart = (double*)  (base + OFF_BP);
    unsigned* cnt   = (unsigned*)(base + OFF_CNT);

    k_prep<<<NN / 64, 256, 0, stream>>>(vec, f2f, VgTh, VgTl, vnorm, cnt);   // 32 blocks
    k_main<<<GRID, TPB, 0, stream>>>(X, W, VgTh, VgTl, vnorm, bias,
                                     lint, bpart, cnt, out);                 // 256 blocks
}

// Round 6
// 125.404 us; speedup vs baseline: 1.4409x; 1.4409x over previous
//
#include <hip/hip_runtime.h>

// (B,N,F,K) = (4096, 2048, 64, 64)
#define NB 4096
#define NN 2048
#define NF 64
#define NK 64

#define NCH 16             // contraction chunks
#define CLEN 128           // cols per chunk
#define KS (CLEN / 32)     // 4 MFMA K-steps
#define RPB 64             // rows per block (4 waves x 16)
#define GRID ((NB / RPB) * NCH)   // 64 x 16 = 1024 blocks = 4/CU

typedef short bf16x8 __attribute__((ext_vector_type(8)));
typedef float f32x4  __attribute__((ext_vector_type(4)));

// ws byte offsets (256B aligned)
#define OFF_VGTH 0                           // ushort [64][2048] hi
#define OFF_VGTL (OFF_VGTH + NK * NN * 2)    // ushort [64][2048] lo
#define OFF_VN   (OFF_VGTL + NK * NN * 2)    // float  [2048]
#define OFF_LINT (OFF_VN + NN * 4)           // float  [4096]
#define OFF_LINP (OFF_LINT + NB * 4)         // float  [16][4096]
#define OFF_DDP  (OFF_LINP + NCH * NB * 4)   // float  [16][4096]
#define OFF_STOT (OFF_DDP + NCH * NB * 4)    // float  [1]
#define OFF_TP   (OFF_STOT + 256)            // float  [16][4096][64] = 16 MB

__device__ inline unsigned short bf16_rtn(float f) {
    unsigned u = __float_as_uint(f);
    return (unsigned short)((u + 0x7fffu + ((u >> 16) & 1u)) >> 16);
}

// ---------- k_prep: gather V rows, bf16 hi/lo split, store transposed [k][i]; zero stot ----------
__global__ __launch_bounds__(256) void k_prep(const float* __restrict__ vec,
                                              const int* __restrict__ f2f,
                                              unsigned short* __restrict__ VgTh,
                                              unsigned short* __restrict__ VgTl,
                                              float* __restrict__ vnorm,
                                              float* __restrict__ stot) {
    __shared__ unsigned short tH[64][72];
    __shared__ unsigned short tL[64][72];
    const int t  = threadIdx.x;
    const int i0 = blockIdx.x * 64;
    if (blockIdx.x == 0 && t == 0) *stot = 0.f;   // re-arm accumulator every launch
    {
        const int il = t >> 2;
        const int sg = (t & 3) * 16;
        const int i  = i0 + il;
        const int f  = f2f[i];
        const float* p = vec + (size_t)i * (NF * NK) + (size_t)f * NK + sg;
        float nsum = 0.f;
        #pragma unroll
        for (int j4 = 0; j4 < 4; ++j4) {
            float4 v = *reinterpret_cast<const float4*>(p + j4 * 4);
            float vv[4] = {v.x, v.y, v.z, v.w};
            #pragma unroll
            for (int e = 0; e < 4; ++e) {
                float x = vv[e];
                nsum = fmaf(x, x, nsum);
                unsigned xb = __float_as_uint(x);
                float hf = __uint_as_float(xb & 0xffff0000u);
                int k = sg + j4 * 4 + e;
                tH[il][k] = (unsigned short)(xb >> 16);
                tL[il][k] = bf16_rtn(x - hf);
            }
        }
        nsum += __shfl_xor(nsum, 1, 64);
        nsum += __shfl_xor(nsum, 2, 64);
        if ((t & 3) == 0) vnorm[i] = nsum;   // vnorm from EXACT fp32 values
    }
    __syncthreads();
    {
        const int k  = t >> 2;
        const int is = (t & 3) * 16;
        unsigned short hb[16], lb[16];
        #pragma unroll
        for (int j = 0; j < 16; ++j) { hb[j] = tH[is + j][k]; lb[j] = tL[is + j][k]; }
        unsigned short* ph = VgTh + (size_t)k * NN + i0 + is;
        unsigned short* pl = VgTl + (size_t)k * NN + i0 + is;
        *reinterpret_cast<uint4*>(ph)     = *reinterpret_cast<uint4*>(hb);
        *reinterpret_cast<uint4*>(ph + 8) = *reinterpret_cast<uint4*>(hb + 8);
        *reinterpret_cast<uint4*>(pl)     = *reinterpret_cast<uint4*>(lb);
        *reinterpret_cast<uint4*>(pl + 8) = *reinterpret_cast<uint4*>(lb + 8);
    }
}

// ---------- k_main: MFMA GEMM chunk with software-pipelined prefetch ----------
// block = 64 rows x 128-col chunk; wave = one 16-row M-tile; grid 1024 = 4 blocks/CU.
__global__ __launch_bounds__(256, 4) void k_main(const float* __restrict__ X,
                                                 const float* __restrict__ Wg,
                                                 const unsigned short* __restrict__ VgTh,
                                                 const unsigned short* __restrict__ VgTl,
                                                 const float* __restrict__ vn,
                                                 float* __restrict__ Tp,
                                                 float* __restrict__ linp,
                                                 float* __restrict__ ddp) {
    const int t    = threadIdx.x;
    const int lane = t & 63;
    const int w    = t >> 6;
    const int rg   = blockIdx.x >> 4;      // 0..63
    const int ch   = blockIdx.x & 15;      // 0..15
    const int r0   = rg * RPB;
    const int c0   = ch * CLEN;

    const int m    = lane & 15;
    const int quad = lane >> 4;
    const int row  = r0 + w * 16 + m;

    const float* xp = X  + (size_t)row * NN + c0 + quad * 8;
    const float* wp = Wg + c0 + quad * 8;
    const float* np = vn + c0 + quad * 8;
    const unsigned short* bhp = VgTh + (size_t)m * NN + c0 + quad * 8;
    const unsigned short* blp = VgTl + (size_t)m * NN + c0 + quad * 8;

    f32x4 acc[4];
    #pragma unroll
    for (int nt = 0; nt < 4; ++nt)
        #pragma unroll
        for (int e = 0; e < 4; ++e) acc[nt][e] = 0.f;
    float lin = 0.f, dd = 0.f;

    // ---- prologue: load step 0 X and B into rotating registers ----
    float4 xa = *reinterpret_cast<const float4*>(xp);
    float4 xb = *reinterpret_cast<const float4*>(xp + 4);
    bf16x8 cbh[4], cbl[4];
    #pragma unroll
    for (int nt = 0; nt < 4; ++nt) {
        cbh[nt] = *reinterpret_cast<const bf16x8*>(bhp + (size_t)nt * 16 * NN);
        cbl[nt] = *reinterpret_cast<const bf16x8*>(blp + (size_t)nt * 16 * NN);
    }

    #pragma unroll
    for (int s = 0; s < KS; ++s) {
        // ---- prefetch step s+1 (clamped; boundary reloads hit L1) ----
        const int sn = (s + 1 < KS) ? s + 1 : s;
        float4 xaN = *reinterpret_cast<const float4*>(xp + sn * 32);
        float4 xbN = *reinterpret_cast<const float4*>(xp + sn * 32 + 4);
        bf16x8 nbh[4], nbl[4];
        #pragma unroll
        for (int nt = 0; nt < 4; ++nt) {
            nbh[nt] = *reinterpret_cast<const bf16x8*>(bhp + (size_t)nt * 16 * NN + sn * 32);
            nbl[nt] = *reinterpret_cast<const bf16x8*>(blp + (size_t)nt * 16 * NN + sn * 32);
        }

        // ---- W / vn (L1-resident, JIT) + fused lin/dd ----
        float4 wa = *reinterpret_cast<const float4*>(wp + s * 32);
        float4 wb = *reinterpret_cast<const float4*>(wp + s * 32 + 4);
        float4 na = *reinterpret_cast<const float4*>(np + s * 32);
        float4 nb = *reinterpret_cast<const float4*>(np + s * 32 + 4);

        float xs8[8] = {xa.x, xa.y, xa.z, xa.w, xb.x, xb.y, xb.z, xb.w};
        float ws8[8] = {wa.x, wa.y, wa.z, wa.w, wb.x, wb.y, wb.z, wb.w};
        float ns8[8] = {na.x, na.y, na.z, na.w, nb.x, nb.y, nb.z, nb.w};

        #pragma unroll
        for (int j = 0; j < 8; ++j) {
            lin = fmaf(xs8[j], ws8[j], lin);
            dd  = fmaf(xs8[j] * xs8[j], ns8[j], dd);
        }

        // ---- A hi/lo split ----
        bf16x8 ah, al;
        #pragma unroll
        for (int j = 0; j < 8; ++j) {
            unsigned ub = __float_as_uint(xs8[j]);
            ah[j] = (short)(ub >> 16);
            float hf = __uint_as_float(ub & 0xffff0000u);
            al[j] = (short)bf16_rtn(xs8[j] - hf);
        }

        // ---- 12 MFMAs on current B ----
        #pragma unroll
        for (int nt = 0; nt < 4; ++nt) {
            acc[nt] = __builtin_amdgcn_mfma_f32_16x16x32_bf16(ah, cbh[nt], acc[nt], 0, 0, 0);
            acc[nt] = __builtin_amdgcn_mfma_f32_16x16x32_bf16(al, cbh[nt], acc[nt], 0, 0, 0);
            acc[nt] = __builtin_amdgcn_mfma_f32_16x16x32_bf16(ah, cbl[nt], acc[nt], 0, 0, 0);
        }

        // ---- rotate ----
        xa = xaN; xb = xbN;
        #pragma unroll
        for (int nt = 0; nt < 4; ++nt) { cbh[nt] = nbh[nt]; cbl[nt] = nbl[nt]; }
    }

    // ---- lin/dd: reduce across quads ----
    lin += __shfl_xor(lin, 16, 64); lin += __shfl_xor(lin, 32, 64);
    dd  += __shfl_xor(dd, 16, 64);  dd  += __shfl_xor(dd, 32, 64);
    if (quad == 0) {
        linp[ch * NB + row] = lin;
        ddp [ch * NB + row] = dd;
    }

    // ---- Tp store: C-layout row = quad*4+r, col = nt*16+m ----
    float* tb = Tp + (size_t)ch * NB * NK;
    #pragma unroll
    for (int nt = 0; nt < 4; ++nt)
        #pragma unroll
        for (int r = 0; r < 4; ++r) {
            int rr = r0 + w * 16 + quad * 4 + r;
            tb[(size_t)rr * NK + nt * 16 + m] = acc[nt][r];
        }
}

// ---------- k_red: sum 16 chunk partials -> lint, block partial -> atomic stot ----------
__global__ __launch_bounds__(256) void k_red(const float* __restrict__ Tp,
                                             const float* __restrict__ linp,
                                             const float* __restrict__ ddp,
                                             float* __restrict__ lint,
                                             float* __restrict__ stot) {
    __shared__ float bp[4];
    int gid = blockIdx.x * 256 + threadIdx.x;
    int row = gid >> 4;
    int g   = gid & 15;
    float4 s = {0.f, 0.f, 0.f, 0.f};
    #pragma unroll
    for (int cc = 0; cc < NCH; ++cc) {
        float4 p = *reinterpret_cast<const float4*>(
            Tp + ((size_t)cc * NB + row) * NK + g * 4);
        s.x += p.x; s.y += p.y; s.z += p.z; s.w += p.w;
    }
    float v = s.x * s.x + s.y * s.y + s.z * s.z + s.w * s.w;
    float l = linp[g * NB + row];
    float d = ddp [g * NB + row];
    #pragma unroll
    for (int mm = 1; mm < 16; mm <<= 1) {
        v += __shfl_xor(v, mm, 64);
        l += __shfl_xor(l, mm, 64);
        d += __shfl_xor(d, mm, 64);
    }
    float sr = (g == 0) ? (v - d) : 0.f;     // per-row interaction partial
    if (g == 0) lint[row] = l;
    // wave-level sum of the 4 rows in this wave
    sr += __shfl_xor(sr, 16, 64);
    sr += __shfl_xor(sr, 32, 64);
    if ((threadIdx.x & 63) == 0) bp[threadIdx.x >> 6] = sr;
    __syncthreads();
    if (threadIdx.x == 0)
        atomicAdd(stot, bp[0] + bp[1] + bp[2] + bp[3]);
}

// ---------- k_final: broadcast ----------
__global__ __launch_bounds__(256) void k_final(const float* __restrict__ lint,
                                               const float* __restrict__ stot,
                                               const float* __restrict__ bptr,
                                               float* __restrict__ out) {
    int b = blockIdx.x * 256 + threadIdx.x;
    out[b] = lint[b] + bptr[0] + 0.5f * stot[0];
}

extern "C" void kernel_launch(void* const* d_in, const int* in_sizes, int n_in,
                              void* d_out, int out_size, void* d_ws, size_t ws_size,
                              hipStream_t stream) {
    const float* X    = (const float*)d_in[0];
    const float* W    = (const float*)d_in[1];
    const float* bias = (const float*)d_in[2];
    const float* vec  = (const float*)d_in[3];
    const int*   f2f  = (const int*)d_in[4];
    float* out = (float*)d_out;

    char* base = (char*)d_ws;
    unsigned short* VgTh = (unsigned short*)(base + OFF_VGTH);
    unsigned short* VgTl = (unsigned short*)(base + OFF_VGTL);
    float* vnorm = (float*)(base + OFF_VN);
    float* lint  = (float*)(base + OFF_LINT);
    float* linp  = (float*)(base + OFF_LINP);
    float* ddp   = (float*)(base + OFF_DDP);
    float* stot  = (float*)(base + OFF_STOT);
    float* Tp    = (float*)(base + OFF_TP);

    k_prep<<<NN / 64, 256, 0, stream>>>(vec, f2f, VgTh, VgTl, vnorm, stot);  // 32 blocks
    k_main<<<GRID, 256, 0, stream>>>(X, W, VgTh, VgTl, vnorm, Tp, linp, ddp); // 1024 blocks
    k_red<<<NB * 16 / 256, 256, 0, stream>>>(Tp, linp, ddp, lint, stot);      // 256 blocks
    k_final<<<NB / 256, 256, 0, stream>>>(lint, stot, bias, out);             // 16 blocks
}